// Round 2
// baseline (554.732 us; speedup 1.0000x reference)
//
#include <hip/hip_runtime.h>

#define NN 100000
#define NE 1600000
#define DD 64

__device__ __forceinline__ float fsig(float x) {
    return __fdividef(1.0f, 1.0f + __expf(-x));
}
__device__ __forceinline__ float ftanh(float x) {
    return __fdividef(2.0f, 1.0f + __expf(-2.0f * x)) - 1.0f;
}
__device__ __forceinline__ unsigned int bf16rne(float a) {
    unsigned int u = __float_as_uint(a);
    return (u + 0x7fffu + ((u >> 16) & 1u)) >> 16;
}

// ---- Phase 1: edge scatter: h_new[dst] += h[src] * w --------------------
// One wave (64 lanes) per edge; lane = channel. Coalesced 256B gather of
// h[src], coalesced atomicAdd row into h_new[dst].
__global__ __launch_bounds__(256) void scatter_k(
    const float* __restrict__ h, const float* __restrict__ ew,
    const int* __restrict__ src, const int* __restrict__ dst,
    float* __restrict__ hnew)
{
    const int lane = threadIdx.x & 63;
    const int e = (blockIdx.x << 2) + (threadIdx.x >> 6);
    if (e >= NE) return;
    const int s = src[e];
    const int d = dst[e];
    const float w = ew[e];
    atomicAdd(&hnew[d * DD + lane], h[s * DD + lane] * w);
}

// ---- Phase 2: GRU cell ---------------------------------------------------
// Weights staged in LDS as bf16 pairs packed along k (k-major layout so
// lanes read consecutive addresses -> 2-way bank aliasing = free).
// Each wave handles 4 nodes; lane = output channel d.
// 16 nodes per 256-thread block-iteration; LDS total 57,344 B -> 2 blk/CU.
__global__ __launch_bounds__(256) void gru_k(
    const float* __restrict__ hnew, const float* __restrict__ h,
    const float* __restrict__ Wih, const float* __restrict__ Whh,
    const float* __restrict__ bih, const float* __restrict__ bhh,
    float* __restrict__ out)
{
    __shared__ unsigned int WtI[32][192];  // [k2][row] bf16x2 (k=2*k2, 2*k2+1)
    __shared__ unsigned int WtH[32][192];
    __shared__ float xs[16][DD];
    __shared__ float hs[16][DD];

    const int tid = threadIdx.x;
    // One-time pack of both weight matrices (coalesced float2 global reads).
    for (int f = tid; f < 192 * 32; f += 256) {
        const int row = f >> 5, k2 = f & 31;
        const float2 wi = *(const float2*)(Wih + row * 64 + 2 * k2);
        const float2 wh = *(const float2*)(Whh + row * 64 + 2 * k2);
        WtI[k2][row] = bf16rne(wi.x) | (bf16rne(wi.y) << 16);
        WtH[k2][row] = bf16rne(wh.x) | (bf16rne(wh.y) << 16);
    }
    __syncthreads();

    const int lane = tid & 63;
    const int warp = tid >> 6;
    const int w4 = warp << 2;

    const float b_ir = bih[lane], b_iz = bih[64 + lane], b_in = bih[128 + lane];
    const float b_hr = bhh[lane], b_hz = bhh[64 + lane], b_hn = bhh[128 + lane];

    // 100000 = 16 * 6250 exactly: no tail guards needed.
    for (int g = blockIdx.x; g < NN / 16; g += gridDim.x) {
        const int nb = g * 16 + w4;
        float hreg[4];
        #pragma unroll
        for (int i = 0; i < 4; ++i) {
            const float xv = hnew[(nb + i) * DD + lane];
            hreg[i] = h[(nb + i) * DD + lane];
            xs[w4 + i][lane] = xv;      // per-wave private rows: no barrier
            hs[w4 + i][lane] = hreg[i];
        }
        float air[4], aiz[4], ain[4], ahr[4], ahz[4], ahn[4];
        #pragma unroll
        for (int i = 0; i < 4; ++i) {
            air[i] = b_ir; aiz[i] = b_iz; ain[i] = b_in;
            ahr[i] = b_hr; ahz[i] = b_hz; ahn[i] = b_hn;
        }
        #pragma unroll 8
        for (int k2 = 0; k2 < 32; ++k2) {
            const unsigned int uir = WtI[k2][lane];
            const unsigned int uiz = WtI[k2][64 + lane];
            const unsigned int uin = WtI[k2][128 + lane];
            const unsigned int uhr = WtH[k2][lane];
            const unsigned int uhz = WtH[k2][64 + lane];
            const unsigned int uhn = WtH[k2][128 + lane];
            const float wir0 = __uint_as_float(uir << 16), wir1 = __uint_as_float(uir & 0xffff0000u);
            const float wiz0 = __uint_as_float(uiz << 16), wiz1 = __uint_as_float(uiz & 0xffff0000u);
            const float win0 = __uint_as_float(uin << 16), win1 = __uint_as_float(uin & 0xffff0000u);
            const float whr0 = __uint_as_float(uhr << 16), whr1 = __uint_as_float(uhr & 0xffff0000u);
            const float whz0 = __uint_as_float(uhz << 16), whz1 = __uint_as_float(uhz & 0xffff0000u);
            const float whn0 = __uint_as_float(uhn << 16), whn1 = __uint_as_float(uhn & 0xffff0000u);
            #pragma unroll
            for (int i = 0; i < 4; ++i) {
                const float2 xv = *(const float2*)(&xs[w4 + i][2 * k2]); // broadcast
                const float2 hv = *(const float2*)(&hs[w4 + i][2 * k2]); // broadcast
                air[i] = fmaf(xv.x, wir0, air[i]); air[i] = fmaf(xv.y, wir1, air[i]);
                aiz[i] = fmaf(xv.x, wiz0, aiz[i]); aiz[i] = fmaf(xv.y, wiz1, aiz[i]);
                ain[i] = fmaf(xv.x, win0, ain[i]); ain[i] = fmaf(xv.y, win1, ain[i]);
                ahr[i] = fmaf(hv.x, whr0, ahr[i]); ahr[i] = fmaf(hv.y, whr1, ahr[i]);
                ahz[i] = fmaf(hv.x, whz0, ahz[i]); ahz[i] = fmaf(hv.y, whz1, ahz[i]);
                ahn[i] = fmaf(hv.x, whn0, ahn[i]); ahn[i] = fmaf(hv.y, whn1, ahn[i]);
            }
        }
        #pragma unroll
        for (int i = 0; i < 4; ++i) {
            const float r  = fsig(air[i] + ahr[i]);
            const float z  = fsig(aiz[i] + ahz[i]);
            const float nv = ftanh(fmaf(r, ahn[i], ain[i]));
            out[(nb + i) * DD + lane] = fmaf(z, hreg[i] - nv, nv); // (1-z)*n + z*h
        }
    }
}

extern "C" void kernel_launch(void* const* d_in, const int* in_sizes, int n_in,
                              void* d_out, int out_size, void* d_ws, size_t ws_size,
                              hipStream_t stream)
{
    const float* h   = (const float*)d_in[0];
    const float* ew  = (const float*)d_in[1];
    const float* Wih = (const float*)d_in[2];
    const float* Whh = (const float*)d_in[3];
    const float* bih = (const float*)d_in[4];
    const float* bhh = (const float*)d_in[5];
    const int*   src = (const int*)d_in[6];
    const int*   dst = (const int*)d_in[7];
    float* out  = (float*)d_out;
    float* hnew = (float*)d_ws;   // 100000*64*4 = 25.6 MB accumulator

    hipMemsetAsync(hnew, 0, (size_t)NN * DD * sizeof(float), stream);
    scatter_k<<<NE / 4, 256, 0, stream>>>(h, ew, src, dst, hnew);
    gru_k<<<512, 256, 0, stream>>>(hnew, h, Wih, Whh, bih, bhh, out);
}

// Round 3
// 505.010 us; speedup vs baseline: 1.0985x; 1.0985x over previous
//
#include <hip/hip_runtime.h>

#define NN 100000
#define NE 1600000
#define DD 64
#define NB1 391   // ceil(NN/256)

__device__ __forceinline__ float fsig(float x) {
    return __fdividef(1.0f, 1.0f + __expf(-x));
}
__device__ __forceinline__ float ftanh(float x) {
    return __fdividef(2.0f, 1.0f + __expf(-2.0f * x)) - 1.0f;
}
__device__ __forceinline__ unsigned int bf16rne(float a) {
    unsigned int u = __float_as_uint(a);
    return (u + 0x7fffu + ((u >> 16) & 1u)) >> 16;
}

// ---- Sort phase: build CSR (edges grouped by dst) -----------------------
// deg/cursor are 400KB -> L2-resident atomics; total atomic count 3.2M
// (vs 102M in the old direct-scatter, which hit the ~294G atomics/s TCC cap).

__global__ __launch_bounds__(256) void hist_k(const int* __restrict__ dst,
                                              unsigned* __restrict__ deg) {
    const int e = blockIdx.x * 256 + threadIdx.x;   // grid covers NE exactly
    atomicAdd(&deg[dst[e]], 1u);
}

// Block-level inclusive scan (Hillis-Steele); writes exclusive partials + block sum.
__global__ __launch_bounds__(256) void scan1_k(const unsigned* __restrict__ deg,
                                               unsigned* __restrict__ part,
                                               unsigned* __restrict__ bsum) {
    __shared__ unsigned s[256];
    const int t = threadIdx.x;
    const int i = blockIdx.x * 256 + t;
    const unsigned v = (i < NN) ? deg[i] : 0u;
    s[t] = v;
    __syncthreads();
    for (int off = 1; off < 256; off <<= 1) {
        const unsigned tmp = (t >= off) ? s[t - off] : 0u;
        __syncthreads();
        s[t] += tmp;
        __syncthreads();
    }
    if (i < NN) part[i] = s[t] - v;            // exclusive
    if (t == 255) bsum[blockIdx.x] = s[255];
}

__global__ __launch_bounds__(512) void scan2_k(const unsigned* __restrict__ bsum,
                                               unsigned* __restrict__ bscan) {
    __shared__ unsigned s[512];
    const int t = threadIdx.x;
    const unsigned v = (t < NB1) ? bsum[t] : 0u;
    s[t] = v;
    __syncthreads();
    for (int off = 1; off < 512; off <<= 1) {
        const unsigned tmp = (t >= off) ? s[t - off] : 0u;
        __syncthreads();
        s[t] += tmp;
        __syncthreads();
    }
    if (t < NB1) bscan[t] = s[t] - v;          // exclusive
}

__global__ __launch_bounds__(256) void scan3_k(const unsigned* __restrict__ part,
                                               const unsigned* __restrict__ bscan,
                                               unsigned* __restrict__ cursor) {
    const int i = blockIdx.x * 256 + threadIdx.x;
    if (i < NN) cursor[i] = part[i] + bscan[blockIdx.x];
}

__global__ __launch_bounds__(256) void place_k(const int* __restrict__ src,
                                               const int* __restrict__ dst,
                                               const float* __restrict__ ew,
                                               unsigned* __restrict__ cursor,
                                               uint2* __restrict__ pairs) {
    const int e = blockIdx.x * 256 + threadIdx.x;   // grid covers NE exactly
    const int d = dst[e];
    const unsigned p = atomicAdd(&cursor[d], 1u);
    pairs[p] = make_uint2((unsigned)src[e], __float_as_uint(ew[e]));
}

// ---- Segment sum: one wave per node, lane = channel, NO atomics ---------
// After place_k, cursor[n] == segment end; start = end - deg[n].
__global__ __launch_bounds__(256) void segsum_k(const float* __restrict__ h,
                                                const uint2* __restrict__ pairs,
                                                const unsigned* __restrict__ cursor,
                                                const unsigned* __restrict__ deg,
                                                float* __restrict__ hnew) {
    const int node = blockIdx.x * 4 + (threadIdx.x >> 6);   // 25000*4 == NN exactly
    const int lane = threadIdx.x & 63;
    const unsigned end = cursor[node];
    const unsigned len = deg[node];
    const unsigned start = end - len;
    float acc = 0.0f;
    for (unsigned base = start; base < end; base += 64) {
        const int m = (int)min(64u, end - base);
        uint2 pr = make_uint2(0u, 0u);
        if (lane < m) pr = pairs[base + lane];   // coalesced 8B/lane
        #pragma unroll 4
        for (int j = 0; j < m; ++j) {
            const int   s = __shfl((int)pr.x, j);
            const float w = __shfl(__uint_as_float(pr.y), j);
            acc = fmaf(w, h[s * DD + lane], acc);   // coalesced 256B row gather
        }
    }
    hnew[node * DD + lane] = acc;
}

// ---- GRU cell -----------------------------------------------------------
// Weights bf16-packed in LDS (48KB); x,h packed together bf16|bf16 per k
// (4KB) -> 53,248B total -> 3 blocks/CU (12 waves). hnew aliases out (no
// __restrict__): each thread reads its row before writing it.
__global__ __launch_bounds__(256, 3) void gru_k(
    const float* hnew, const float* __restrict__ h,
    const float* __restrict__ Wih, const float* __restrict__ Whh,
    const float* __restrict__ bih, const float* __restrict__ bhh,
    float* out)
{
    __shared__ unsigned WtI[32][192];  // [k2][row], bf16x2 along k
    __shared__ unsigned WtH[32][192];
    __shared__ unsigned xh[16][64];    // (bf16(x)<<16)|bf16(h), per node per k

    const int tid = threadIdx.x;
    for (int f = tid; f < 192 * 32; f += 256) {
        const int row = f >> 5, k2 = f & 31;
        const float2 wi = *(const float2*)(Wih + row * 64 + 2 * k2);
        const float2 wh = *(const float2*)(Whh + row * 64 + 2 * k2);
        WtI[k2][row] = bf16rne(wi.x) | (bf16rne(wi.y) << 16);
        WtH[k2][row] = bf16rne(wh.x) | (bf16rne(wh.y) << 16);
    }
    __syncthreads();

    const int lane = tid & 63;
    const int w4 = (tid >> 6) << 2;

    const float b_ir = bih[lane], b_iz = bih[64 + lane], b_in = bih[128 + lane];
    const float b_hr = bhh[lane], b_hz = bhh[64 + lane], b_hn = bhh[128 + lane];

    for (int g = blockIdx.x; g < NN / 16; g += gridDim.x) {
        const int nb = g * 16 + w4;
        float hreg[4];
        #pragma unroll
        for (int i = 0; i < 4; ++i) {
            const float xv = hnew[(nb + i) * DD + lane];
            hreg[i] = h[(nb + i) * DD + lane];
            xh[w4 + i][lane] = (bf16rne(xv) << 16) | bf16rne(hreg[i]);  // wave-private rows
        }
        float air[4], aiz[4], ain[4], ahr[4], ahz[4], ahn[4];
        #pragma unroll
        for (int i = 0; i < 4; ++i) {
            air[i] = b_ir; aiz[i] = b_iz; ain[i] = b_in;
            ahr[i] = b_hr; ahz[i] = b_hz; ahn[i] = b_hn;
        }
        #pragma unroll 8
        for (int k2 = 0; k2 < 32; ++k2) {
            const unsigned uir = WtI[k2][lane];
            const unsigned uiz = WtI[k2][64 + lane];
            const unsigned uin = WtI[k2][128 + lane];
            const unsigned uhr = WtH[k2][lane];
            const unsigned uhz = WtH[k2][64 + lane];
            const unsigned uhn = WtH[k2][128 + lane];
            const float wir0 = __uint_as_float(uir << 16), wir1 = __uint_as_float(uir & 0xffff0000u);
            const float wiz0 = __uint_as_float(uiz << 16), wiz1 = __uint_as_float(uiz & 0xffff0000u);
            const float win0 = __uint_as_float(uin << 16), win1 = __uint_as_float(uin & 0xffff0000u);
            const float whr0 = __uint_as_float(uhr << 16), whr1 = __uint_as_float(uhr & 0xffff0000u);
            const float whz0 = __uint_as_float(uhz << 16), whz1 = __uint_as_float(uhz & 0xffff0000u);
            const float whn0 = __uint_as_float(uhn << 16), whn1 = __uint_as_float(uhn & 0xffff0000u);
            #pragma unroll
            for (int i = 0; i < 4; ++i) {
                const uint2 u2 = *(const uint2*)(&xh[w4 + i][2 * k2]);  // broadcast b64
                const float x0 = __uint_as_float(u2.x & 0xffff0000u);
                const float h0 = __uint_as_float(u2.x << 16);
                const float x1 = __uint_as_float(u2.y & 0xffff0000u);
                const float h1 = __uint_as_float(u2.y << 16);
                air[i] = fmaf(x0, wir0, air[i]); air[i] = fmaf(x1, wir1, air[i]);
                aiz[i] = fmaf(x0, wiz0, aiz[i]); aiz[i] = fmaf(x1, wiz1, aiz[i]);
                ain[i] = fmaf(x0, win0, ain[i]); ain[i] = fmaf(x1, win1, ain[i]);
                ahr[i] = fmaf(h0, whr0, ahr[i]); ahr[i] = fmaf(h1, whr1, ahr[i]);
                ahz[i] = fmaf(h0, whz0, ahz[i]); ahz[i] = fmaf(h1, whz1, ahz[i]);
                ahn[i] = fmaf(h0, whn0, ahn[i]); ahn[i] = fmaf(h1, whn1, ahn[i]);
            }
        }
        #pragma unroll
        for (int i = 0; i < 4; ++i) {
            const float r  = fsig(air[i] + ahr[i]);
            const float z  = fsig(aiz[i] + ahz[i]);
            const float nv = ftanh(fmaf(r, ahn[i], ain[i]));
            out[(nb + i) * DD + lane] = fmaf(z, hreg[i] - nv, nv); // (1-z)*n + z*h
        }
    }
}

extern "C" void kernel_launch(void* const* d_in, const int* in_sizes, int n_in,
                              void* d_out, int out_size, void* d_ws, size_t ws_size,
                              hipStream_t stream)
{
    const float* h   = (const float*)d_in[0];
    const float* ew  = (const float*)d_in[1];
    const float* Wih = (const float*)d_in[2];
    const float* Whh = (const float*)d_in[3];
    const float* bih = (const float*)d_in[4];
    const float* bhh = (const float*)d_in[5];
    const int*   src = (const int*)d_in[6];
    const int*   dst = (const int*)d_in[7];
    float* out = (float*)d_out;

    // ws layout (total ~14.0 MB, under the 25.6 MB proven available)
    char* ws = (char*)d_ws;
    unsigned* deg    = (unsigned*)(ws);                 // 400,000 B
    unsigned* cursor = (unsigned*)(ws + 400000);        // 400,000 B
    unsigned* part   = (unsigned*)(ws + 800000);        // 400,000 B
    unsigned* bsum   = (unsigned*)(ws + 1200000);       //   2,048 B
    unsigned* bscan  = (unsigned*)(ws + 1202048);       //   2,048 B
    uint2*    pairs  = (uint2*)   (ws + 1204224);       // 12.8 MB

    hipMemsetAsync(deg, 0, NN * sizeof(unsigned), stream);
    hist_k <<<NE / 256, 256, 0, stream>>>(dst, deg);
    scan1_k<<<NB1, 256, 0, stream>>>(deg, part, bsum);
    scan2_k<<<1, 512, 0, stream>>>(bsum, bscan);
    scan3_k<<<NB1, 256, 0, stream>>>(part, bscan, cursor);
    place_k<<<NE / 256, 256, 0, stream>>>(src, dst, ew, cursor, pairs);
    segsum_k<<<NN / 4, 256, 0, stream>>>(h, pairs, cursor, deg, out); // out = hnew scratch
    gru_k  <<<768, 256, 0, stream>>>(out, h, Wih, Whh, bih, bhh, out);
}